// Round 21
// baseline (128.456 us; speedup 1.0000x reference)
//
#include <hip/hip_runtime.h>

// SelfAttention fused pipeline, MI355X gfx950. bf16 MFMA compute, f32 I/O.
// R21 = green R20 + SPECULATIVE exp2: P computed with m_old concurrently with
// the max-reduce (no control dependency); rare defer-max branch recomputes.
// Bit-identical on both paths (untaken = old code's unchanged-m exp2; taken =
// recompute, matching old code). Tile 0 always takes the branch (spec values
// inf, discarded). Serial chain shortened by the max->exp2 wait.
//
//  K0  cvt_all: x, w_qkv, w_out -> bf16 (one dispatch)
//  K1  gemm_bt<0>: qkv = xb @ wqb^T; epilogue scatters Qb (x scale*log2e),
//      Kb/Vw as swizzled 8KB tile images (conflict-free K via row-bit3 XOR)
//  K2  attn_fwd: flash attn, 4 waves x 16 q-rows, KV tile 64; S pipelined
//      one tile ahead; online defer-max softmax; P in-register PV (16x16x16).
//  K3  gemm_bt<1>: out = Of @ wob^T + b_out  (f32 out)
//
// ws: [Qb 8M][Kb 8M][Vw 8M][xb|Of 8M][wqb 6M][wob 2M] = 40 MB

typedef __bf16 bf16;
typedef __bf16 bf16x4 __attribute__((ext_vector_type(4)));
typedef __bf16 bf16x8 __attribute__((ext_vector_type(8)));
typedef float  f32x4 __attribute__((ext_vector_type(4)));
typedef unsigned u32x2 __attribute__((ext_vector_type(2)));

#define MFMA32(A, B, C) __builtin_amdgcn_mfma_f32_16x16x32_bf16((A), (B), (C), 0, 0, 0)

static constexpr long QOFF  = 0;
static constexpr long KOFF  = 8388608;
static constexpr long VOFF  = 16777216;
static constexpr long FOFF  = 25165824;   // xb during gemm0, Of afterwards
static constexpr long WQOFF = 33554432;
static constexpr long WOOFF = 39845888;

// q scale: 1/sqrt(1024) * log2(e)  (softmax in exp2 domain)
#define QSCALE 0.045084222f

__device__ __forceinline__ void gl16(const bf16* g, bf16* l) {
  __builtin_amdgcn_global_load_lds((const __attribute__((address_space(1))) void*)g,
                                   (__attribute__((address_space(3))) void*)l, 16, 0, 0);
}

__device__ __forceinline__ f32x4 mfma16(bf16x4 a, bf16x4 b, f32x4 c) {
  asm("v_mfma_f32_16x16x16_bf16 %0, %1, %2, %0" : "+v"(c) : "v"(a), "v"(b));
  return c;
}

__device__ __forceinline__ float exp2fast(float x) {
#if __has_builtin(__builtin_amdgcn_exp2f)
  return __builtin_amdgcn_exp2f(x);
#else
  return exp2f(x);
#endif
}

__device__ __forceinline__ float max3f(float a, float b, float c) {
  return fmaxf(fmaxf(a, b), c);   // clang fuses to v_max3_f32
}

// max over lane pairs (l, l^32) via permlane32_swap builtin (both regs defined).
__device__ __forceinline__ float xmax32(float t) {
#if __has_builtin(__builtin_amdgcn_permlane32_swap)
  const unsigned u = __builtin_bit_cast(unsigned, t);
  const u32x2 r = __builtin_amdgcn_permlane32_swap(u, u, false, false);
  return fmaxf(__builtin_bit_cast(float, r.x), __builtin_bit_cast(float, r.y));
#else
  return fmaxf(t, __shfl_xor(t, 32));
#endif
}

// max over lane pairs (l, l^16) via permlane16_swap builtin.
__device__ __forceinline__ float xmax16(float t) {
#if __has_builtin(__builtin_amdgcn_permlane16_swap)
  const unsigned u = __builtin_bit_cast(unsigned, t);
  const u32x2 r = __builtin_amdgcn_permlane16_swap(u, u, false, false);
  return fmaxf(__builtin_bit_cast(float, r.x), __builtin_bit_cast(float, r.y));
#else
  return fmaxf(t, __shfl_xor(t, 16));
#endif
}

// one dispatch: 1048576 chunks of 8 f32 -> bf16
__global__ __launch_bounds__(256)
void cvt_all(const float* __restrict__ x, const float* __restrict__ wq,
             const float* __restrict__ wo, bf16* __restrict__ xb,
             bf16* __restrict__ wqb, bf16* __restrict__ wob) {
  const int i = blockIdx.x * 256 + threadIdx.x;
  const float* in; bf16* out; long j;
  if (i < 524288)      { in = x;  out = xb;  j = i; }
  else if (i < 917504) { in = wq; out = wqb; j = i - 524288; }
  else                 { in = wo; out = wob; j = i - 917504; }
  const f32x4 v0 = *(const f32x4*)(in + j * 8);
  const f32x4 v1 = *(const f32x4*)(in + j * 8 + 4);
  bf16x8 o;
#pragma unroll
  for (int k = 0; k < 4; ++k) { o[k] = (bf16)v0[k]; o[k + 4] = (bf16)v1[k]; }
  *(bf16x8*)(out + j * 8) = o;
}

// C[M,N] = A[M,K] * B[N,K]^T, K=1024, bf16 inputs. 128x128 tile, BK=32, 4 waves.
// global_load_lds staging into linear [128][32] LDS; single barrier per K-step.
template <int MODE> // 0: qkv scatter epilogue; 1: f32+bias epilogue
__global__ __launch_bounds__(256, 3)
void gemm_bt(const bf16* __restrict__ Ag, const bf16* __restrict__ Bg,
             float* __restrict__ outp, const float* __restrict__ bias,
             char* __restrict__ wsp)
{
  constexpr int K  = 1024;
  constexpr int NT = K / 32;
  const int bm = blockIdx.y, bn = blockIdx.x;
  const int tid  = threadIdx.x;
  const int lane = tid & 63;
  const int l15  = lane & 15, g = lane >> 4;
  const int wave = tid >> 6;
  const int wr = wave >> 1, wc = wave & 1;

  __shared__ __align__(16) bf16 Ab[2][4096];   // linear [128][32]
  __shared__ __align__(16) bf16 Bb[2][4096];

  const int srow0 = wave * 32 + (lane >> 2);
  const int scol  = (lane & 3) * 8;
  const bf16* apg = Ag + (long)(bm * 128 + srow0) * K + scol;
  const bf16* bpg = Bg + (long)(bn * 128 + srow0) * K + scol;

  auto stage = [&](int t, int buf) {
#pragma unroll
    for (int j = 0; j < 2; ++j) {
      gl16(apg + t * 32 + j * (16 * K), &Ab[buf][(wave * 2 + j) * 512]);
      gl16(bpg + t * 32 + j * (16 * K), &Bb[buf][(wave * 2 + j) * 512]);
    }
  };

  f32x4 acc[4][4] = {};

  stage(0, 0);
  __syncthreads();

#pragma unroll 2
  for (int t = 0; t < NT; ++t) {
    const int buf = t & 1;
    if (t + 1 < NT) stage(t + 1, buf ^ 1);
    bf16x8 af[4], bfv[4];
#pragma unroll
    for (int mf = 0; mf < 4; ++mf)
      af[mf] = *(const bf16x8*)&Ab[buf][(wr * 64 + mf * 16 + l15) * 32 + g * 8];
#pragma unroll
    for (int nf = 0; nf < 4; ++nf)
      bfv[nf] = *(const bf16x8*)&Bb[buf][(wc * 64 + nf * 16 + l15) * 32 + g * 8];
#pragma unroll
    for (int mf = 0; mf < 4; ++mf)
#pragma unroll
      for (int nf = 0; nf < 4; ++nf)
        acc[mf][nf] = MFMA32(af[mf], bfv[nf], acc[mf][nf]);
    __syncthreads();
  }

  // C/D layout: col = lane&15, row = (lane>>4)*4 + reg
  if constexpr (MODE == 0) {
    bf16* Qb = (bf16*)(wsp + QOFF);
    bf16* Kb = (bf16*)(wsp + KOFF);
    bf16* Vw = (bf16*)(wsp + VOFF);
#pragma unroll
    for (int nf = 0; nf < 4; ++nf) {
      const int colb = bn * 128 + wc * 64 + nf * 16 + l15; // e in [0,3072)
      const int s = colb >> 10;          // 0:q 1:k 2:v
      const int h = (colb >> 6) & 15;
      const int d = colb & 63;
#pragma unroll
      for (int mf = 0; mf < 4; ++mf) {
        const int rowb = bm * 128 + wr * 64 + mf * 16 + g * 4;  // rr base
        const int bb = rowb >> 11;
        const int lib = rowb & 2047;
        if (s == 2) {
          // V: group = (lc>>3)^(d&7); pos = (lc&7)^(((d>>3)&1)<<2).
          const int lcb = lib & 63;
          const int swb = (((lcb >> 3) ^ (d & 7)) << 3) |
                          ((lcb & 7) ^ (((d >> 3) & 1) << 2));
          bf16x4 pv;
#pragma unroll
          for (int rr = 0; rr < 4; ++rr) pv[rr] = (bf16)acc[mf][nf][rr];
          *(bf16x4*)&Vw[(long)(bb * 16 + h) * 131072 + (lib >> 6) * 4096 +
                        d * 64 + swb] = pv;
        } else if (s == 0) {
#pragma unroll
          for (int rr = 0; rr < 4; ++rr)
            Qb[(long)((bb * 16 + h) * 2048 + lib + rr) * 64 + d] =
              (bf16)(acc[mf][nf][rr] * QSCALE);
        } else {
          // K: group = ((d>>3)^(li&7)) ^ (((li>>3)&1)<<2); pos = d&7.
#pragma unroll
          for (int rr = 0; rr < 4; ++rr) {
            const int li = lib + rr;
            const int sw = (((((d >> 3) ^ (li & 7)) ^ (((li >> 3) & 1) << 2)) << 3)
                            | (d & 7));
            Kb[(long)((bb * 16 + h) * 2048 + li) * 64 + sw] = (bf16)acc[mf][nf][rr];
          }
        }
      }
    }
  } else {
#pragma unroll
    for (int nf = 0; nf < 4; ++nf) {
      const int colg = bn * 128 + wc * 64 + nf * 16 + l15;
      const float bv = bias[colg];
#pragma unroll
      for (int mf = 0; mf < 4; ++mf) {
#pragma unroll
        for (int rr = 0; rr < 4; ++rr) {
          const int rowg = bm * 128 + wr * 64 + mf * 16 + g * 4 + rr;
          outp[(long)rowg * 1024 + colg] = acc[mf][nf][rr] + bv;
        }
      }
    }
  }
}

// Flash attention, swapped-operand, pipelined: S(t+1) MFMAs issued before
// softmax(t). K staged 2-ahead, V 1-ahead. Online defer-max softmax with
// SPECULATIVE exp2 (computed with m_old in parallel with the max reduce;
// rare branch recomputes). T5 setprio; conflict-free K; pure-VALU max reduce.
__global__ __launch_bounds__(256, 4)
void attn_fwd(const bf16* __restrict__ Q, const bf16* __restrict__ Kw,
              const bf16* __restrict__ Vw, bf16* __restrict__ Of)
{
  const int bid  = blockIdx.x;
  const int slot = bid >> 3;
  const int bh   = (bid & 7) * 4 + (slot >> 5);
  const int qt   = slot & 31;
  const int lane = threadIdx.x & 63;
  const int wave = threadIdx.x >> 6;
  const int l15  = lane & 15, g = lane >> 4;

  const bf16* Qh = Q  + (long)bh * 131072;
  const bf16* Ks = Kw + (long)bh * 131072;
  const bf16* Vs = Vw + (long)bh * 131072;

  __shared__ __align__(16) bf16 Klds[2][4096];
  __shared__ __align__(16) bf16 Vlds[2][4096];

  const int q0 = qt * 64 + wave * 16;

  bf16x8 qf[2];
#pragma unroll
  for (int ds = 0; ds < 2; ++ds)
    qf[ds] = *(const bf16x8*)(Qh + (q0 + l15) * 64 + ds * 32 + g * 8);

  int ke[2], ve[4];
#pragma unroll
  for (int ds = 0; ds < 2; ++ds)
    ke[ds] = l15 * 64 + ((((ds * 4 + g) ^ (l15 & 7)) ^ (((l15 >> 3) & 1) << 2)) << 3);
  const int hsw = ((g & 1) ^ ((l15 >> 3) & 1)) << 2;
#pragma unroll
  for (int kg = 0; kg < 4; ++kg)
    ve[kg] = l15 * 64 + (((2 * kg + (g >> 1)) ^ (l15 & 7)) << 3) + hsw;

  auto stageK = [&](int t, int buf) {
    const bf16* sk = Ks + t * 4096 + wave * 1024 + lane * 8;
    gl16(sk,       &Klds[buf][wave * 1024]);
    gl16(sk + 512, &Klds[buf][wave * 1024 + 512]);
  };
  auto stageV = [&](int t, int buf) {
    const bf16* sv = Vs + t * 4096 + wave * 1024 + lane * 8;
    gl16(sv,       &Vlds[buf][wave * 1024]);
    gl16(sv + 512, &Vlds[buf][wave * 1024 + 512]);
  };

  f32x4 o[4] = {};
  float m = -1e30f, ps = 0.f;
  f32x4 sfA[4], sfB[4];

#define COMPUTE_S(BUF, SF) do {                                               \
  __builtin_amdgcn_s_setprio(1);                                              \
  _Pragma("unroll")                                                           \
  for (int kg = 0; kg < 4; ++kg) {                                            \
    SF[kg] = f32x4{0.f, 0.f, 0.f, 0.f};                                       \
    _Pragma("unroll")                                                         \
    for (int ds = 0; ds < 2; ++ds) {                                          \
      const bf16x8 kf = *(const bf16x8*)&Klds[BUF][kg * 1024 + ke[ds]];       \
      SF[kg] = MFMA32(kf, qf[ds], SF[kg]);                                    \
    }                                                                         \
  }                                                                           \
  __builtin_amdgcn_s_setprio(0);                                              \
} while (0)

#define PCOMPUTE(SFC) do {                                                    \
  rs0 = 0.f; rs1 = 0.f; rs2 = 0.f; rs3 = 0.f;                                 \
  _Pragma("unroll")                                                           \
  for (int kg = 0; kg < 4; ++kg) {                                            \
    const float p0 = exp2fast(SFC[kg][0] - m);                                \
    const float p1 = exp2fast(SFC[kg][1] - m);                                \
    const float p2 = exp2fast(SFC[kg][2] - m);                                \
    const float p3 = exp2fast(SFC[kg][3] - m);                                \
    rs0 += p0; rs1 += p1; rs2 += p2; rs3 += p3;                               \
    pa[kg][0] = (bf16)p0; pa[kg][1] = (bf16)p1;                               \
    pa[kg][2] = (bf16)p2; pa[kg][3] = (bf16)p3;                               \
  }                                                                           \
} while (0)

#define ATTN_BODY(T, SFC, SFN) do {                                           \
  if ((T) <= 29) stageK((T) + 2, (T) & 1);                                    \
  if ((T) <= 30) stageV((T) + 1, ((T) + 1) & 1);                              \
  if ((T) <= 30) COMPUTE_S(((T) + 1) & 1, SFN);                               \
  const float t0 = max3f(SFC[0][0], SFC[0][1], SFC[0][2]);                    \
  const float t1 = max3f(SFC[0][3], SFC[1][0], SFC[1][1]);                    \
  const float t2 = max3f(SFC[1][2], SFC[1][3], SFC[2][0]);                    \
  const float t3 = max3f(SFC[2][1], SFC[2][2], SFC[2][3]);                    \
  const float t4 = max3f(SFC[3][0], SFC[3][1], SFC[3][2]);                    \
  float tm = fmaxf(max3f(t0, t1, t2), max3f(t3, t4, SFC[3][3]));              \
  bf16x4 pa[4];                                                               \
  float rs0, rs1, rs2, rs3;                                                   \
  PCOMPUTE(SFC);              /* speculative: uses m_old, overlaps reduce */  \
  tm = xmax16(tm);                                                            \
  tm = xmax32(tm);                                                            \
  if (!__all(tm <= m + 8.f)) {                                                \
    const float nm = fmaxf(m, tm);                                            \
    const float al = exp2fast(m - nm);                                        \
    m = nm;                                                                   \
    ps *= al;                                                                 \
    _Pragma("unroll")                                                         \
    for (int dg = 0; dg < 4; ++dg)                                            \
      _Pragma("unroll")                                                       \
      for (int rr = 0; rr < 4; ++rr) o[dg][rr] *= al;                         \
    PCOMPUTE(SFC);            /* rare: recompute with new m */                \
  }                                                                           \
  ps += (rs0 + rs1) + (rs2 + rs3);                                            \
  __builtin_amdgcn_s_setprio(1);                                              \
  _Pragma("unroll")                                                           \
  for (int kg = 0; kg < 4; ++kg)                                              \
    _Pragma("unroll")                                                         \
    for (int dg = 0; dg < 4; ++dg) {                                          \
      const bf16x4 vb = *(const bf16x4*)&Vlds[(T) & 1][dg * 1024 + ve[kg]];   \
      o[dg] = mfma16(vb, pa[kg], o[dg]);                                      \
    }                                                                         \
  __builtin_amdgcn_s_setprio(0);                                              \
  __syncthreads();                                                            \
} while (0)

  // prologue: K0,V0 staged+drained; S(0) computed; K1 staged+drained
  stageK(0, 0);
  stageV(0, 0);
  __syncthreads();
  stageK(1, 1);
  COMPUTE_S(0, sfA);
  __syncthreads();

#pragma unroll 1
  for (int tp = 0; tp < 32; tp += 2) {
    ATTN_BODY(tp, sfA, sfB);
    ATTN_BODY(tp + 1, sfB, sfA);
  }

#undef ATTN_BODY
#undef PCOMPUTE
#undef COMPUTE_S

  ps += __shfl_xor(ps, 16);
  ps += __shfl_xor(ps, 32);
  const float inv = 1.f / ps;

  const int b = bh >> 4, h = bh & 15;
#pragma unroll
  for (int dg = 0; dg < 4; ++dg) {
    bf16x4 ov;
#pragma unroll
    for (int rr = 0; rr < 4; ++rr) ov[rr] = (bf16)(o[dg][rr] * inv);
    *(bf16x4*)(Of + (long)(b * 2048 + q0 + l15) * 1024 + h * 64 + dg * 16 + g * 4) = ov;
  }
}

extern "C" void kernel_launch(void* const* d_in, const int* in_sizes, int n_in,
                              void* d_out, int out_size, void* d_ws, size_t ws_size,
                              hipStream_t stream)
{
  (void)in_sizes; (void)n_in; (void)out_size; (void)ws_size;
  const float* x     = (const float*)d_in[0];
  const float* w_qkv = (const float*)d_in[1];
  const float* w_out = (const float*)d_in[2];
  const float* b_out = (const float*)d_in[3];
  float* out = (float*)d_out;
  char*  ws  = (char*)d_ws;

  bf16* Qb  = (bf16*)(ws + QOFF);
  bf16* Kb  = (bf16*)(ws + KOFF);
  bf16* Vw  = (bf16*)(ws + VOFF);
  bf16* xb  = (bf16*)(ws + FOFF);
  bf16* Ofb = (bf16*)(ws + FOFF);   // reuses xb region after gemm0 completes
  bf16* wqb = (bf16*)(ws + WQOFF);
  bf16* wob = (bf16*)(ws + WOOFF);

  cvt_all<<<dim3(4096), 256, 0, stream>>>(x, w_qkv, w_out, xb, wqb, wob);
  gemm_bt<0><<<dim3(24, 32), 256, 0, stream>>>(xb, wqb, nullptr, nullptr, ws);
  attn_fwd<<<dim3(1024), 256, 0, stream>>>(Qb, Kb, Vw, Ofb);
  gemm_bt<1><<<dim3(8, 32), 256, 0, stream>>>(Ofb, wob, out, b_out, ws);
}

// Round 22
// 127.933 us; speedup vs baseline: 1.0041x; 1.0041x over previous
//
#include <hip/hip_runtime.h>

// SelfAttention fused pipeline, MI355X gfx950. bf16 MFMA compute, f32 I/O.
// R22 = byte-exact revert to green R20 (session best, 128.05 us). R21's
// speculative exp2 was neutral-negative (chain is issue-bound; compiler had
// already interleaved trans/VALU streams). FINAL configuration.
//
// Session: 339.6 -> 128.05 us. Wins: bf16 MFMA pipeline w/ fused scales,
// swapped-operand flash attn w/ in-register P (16x16x16 PV), global_load_lds
// staging everywhere, conflict-free K-tile swizzle (-4.2us), vectorized V
// epilogue (-3.7us), permlane32/16 pure-VALU softmax reduce (-4.3us).
// Closed: 128-row attn blocks (3 unexplained NaNs), fixed-shift softmax
// (convicted R9), gemm tile/occupancy variants (neutral or regressed).
//
//  K0  cvt_all: x, w_qkv, w_out -> bf16 (one dispatch)
//  K1  gemm_bt<0>: qkv = xb @ wqb^T; epilogue scatters Qb (x scale*log2e),
//      Kb/Vw as swizzled 8KB tile images (conflict-free K via row-bit3 XOR)
//  K2  attn_fwd: flash attn, 4 waves x 16 q-rows, KV tile 64; S pipelined
//      one tile ahead; online defer-max softmax; P in-register PV (16x16x16).
//  K3  gemm_bt<1>: out = Of @ wob^T + b_out  (f32 out)
//
// ws: [Qb 8M][Kb 8M][Vw 8M][xb|Of 8M][wqb 6M][wob 2M] = 40 MB

typedef __bf16 bf16;
typedef __bf16 bf16x4 __attribute__((ext_vector_type(4)));
typedef __bf16 bf16x8 __attribute__((ext_vector_type(8)));
typedef float  f32x4 __attribute__((ext_vector_type(4)));
typedef unsigned u32x2 __attribute__((ext_vector_type(2)));

#define MFMA32(A, B, C) __builtin_amdgcn_mfma_f32_16x16x32_bf16((A), (B), (C), 0, 0, 0)

static constexpr long QOFF  = 0;
static constexpr long KOFF  = 8388608;
static constexpr long VOFF  = 16777216;
static constexpr long FOFF  = 25165824;   // xb during gemm0, Of afterwards
static constexpr long WQOFF = 33554432;
static constexpr long WOOFF = 39845888;

// q scale: 1/sqrt(1024) * log2(e)  (softmax in exp2 domain)
#define QSCALE 0.045084222f

__device__ __forceinline__ void gl16(const bf16* g, bf16* l) {
  __builtin_amdgcn_global_load_lds((const __attribute__((address_space(1))) void*)g,
                                   (__attribute__((address_space(3))) void*)l, 16, 0, 0);
}

__device__ __forceinline__ f32x4 mfma16(bf16x4 a, bf16x4 b, f32x4 c) {
  asm("v_mfma_f32_16x16x16_bf16 %0, %1, %2, %0" : "+v"(c) : "v"(a), "v"(b));
  return c;
}

__device__ __forceinline__ float exp2fast(float x) {
#if __has_builtin(__builtin_amdgcn_exp2f)
  return __builtin_amdgcn_exp2f(x);
#else
  return exp2f(x);
#endif
}

__device__ __forceinline__ float max3f(float a, float b, float c) {
  return fmaxf(fmaxf(a, b), c);   // clang fuses to v_max3_f32
}

// max over lane pairs (l, l^32) via permlane32_swap builtin (both regs defined).
__device__ __forceinline__ float xmax32(float t) {
#if __has_builtin(__builtin_amdgcn_permlane32_swap)
  const unsigned u = __builtin_bit_cast(unsigned, t);
  const u32x2 r = __builtin_amdgcn_permlane32_swap(u, u, false, false);
  return fmaxf(__builtin_bit_cast(float, r.x), __builtin_bit_cast(float, r.y));
#else
  return fmaxf(t, __shfl_xor(t, 32));
#endif
}

// max over lane pairs (l, l^16) via permlane16_swap builtin: odd 16-lane rows
// of op0 swap with even rows of op1; with both = t, {r.x, r.y} = {t[i], t[i^16]}
// (order lane-dependent) -> fmax is the exact pairwise max.
__device__ __forceinline__ float xmax16(float t) {
#if __has_builtin(__builtin_amdgcn_permlane16_swap)
  const unsigned u = __builtin_bit_cast(unsigned, t);
  const u32x2 r = __builtin_amdgcn_permlane16_swap(u, u, false, false);
  return fmaxf(__builtin_bit_cast(float, r.x), __builtin_bit_cast(float, r.y));
#else
  return fmaxf(t, __shfl_xor(t, 16));
#endif
}

// one dispatch: 1048576 chunks of 8 f32 -> bf16
__global__ __launch_bounds__(256)
void cvt_all(const float* __restrict__ x, const float* __restrict__ wq,
             const float* __restrict__ wo, bf16* __restrict__ xb,
             bf16* __restrict__ wqb, bf16* __restrict__ wob) {
  const int i = blockIdx.x * 256 + threadIdx.x;
  const float* in; bf16* out; long j;
  if (i < 524288)      { in = x;  out = xb;  j = i; }
  else if (i < 917504) { in = wq; out = wqb; j = i - 524288; }
  else                 { in = wo; out = wob; j = i - 917504; }
  const f32x4 v0 = *(const f32x4*)(in + j * 8);
  const f32x4 v1 = *(const f32x4*)(in + j * 8 + 4);
  bf16x8 o;
#pragma unroll
  for (int k = 0; k < 4; ++k) { o[k] = (bf16)v0[k]; o[k + 4] = (bf16)v1[k]; }
  *(bf16x8*)(out + j * 8) = o;
}

// C[M,N] = A[M,K] * B[N,K]^T, K=1024, bf16 inputs. 128x128 tile, BK=32, 4 waves.
// global_load_lds staging into linear [128][32] LDS; single barrier per K-step.
template <int MODE> // 0: qkv scatter epilogue; 1: f32+bias epilogue
__global__ __launch_bounds__(256, 3)
void gemm_bt(const bf16* __restrict__ Ag, const bf16* __restrict__ Bg,
             float* __restrict__ outp, const float* __restrict__ bias,
             char* __restrict__ wsp)
{
  constexpr int K  = 1024;
  constexpr int NT = K / 32;
  const int bm = blockIdx.y, bn = blockIdx.x;
  const int tid  = threadIdx.x;
  const int lane = tid & 63;
  const int l15  = lane & 15, g = lane >> 4;
  const int wave = tid >> 6;
  const int wr = wave >> 1, wc = wave & 1;

  __shared__ __align__(16) bf16 Ab[2][4096];   // linear [128][32]
  __shared__ __align__(16) bf16 Bb[2][4096];

  const int srow0 = wave * 32 + (lane >> 2);
  const int scol  = (lane & 3) * 8;
  const bf16* apg = Ag + (long)(bm * 128 + srow0) * K + scol;
  const bf16* bpg = Bg + (long)(bn * 128 + srow0) * K + scol;

  auto stage = [&](int t, int buf) {
#pragma unroll
    for (int j = 0; j < 2; ++j) {
      gl16(apg + t * 32 + j * (16 * K), &Ab[buf][(wave * 2 + j) * 512]);
      gl16(bpg + t * 32 + j * (16 * K), &Bb[buf][(wave * 2 + j) * 512]);
    }
  };

  f32x4 acc[4][4] = {};

  stage(0, 0);
  __syncthreads();

#pragma unroll 2
  for (int t = 0; t < NT; ++t) {
    const int buf = t & 1;
    if (t + 1 < NT) stage(t + 1, buf ^ 1);
    bf16x8 af[4], bfv[4];
#pragma unroll
    for (int mf = 0; mf < 4; ++mf)
      af[mf] = *(const bf16x8*)&Ab[buf][(wr * 64 + mf * 16 + l15) * 32 + g * 8];
#pragma unroll
    for (int nf = 0; nf < 4; ++nf)
      bfv[nf] = *(const bf16x8*)&Bb[buf][(wc * 64 + nf * 16 + l15) * 32 + g * 8];
#pragma unroll
    for (int mf = 0; mf < 4; ++mf)
#pragma unroll
      for (int nf = 0; nf < 4; ++nf)
        acc[mf][nf] = MFMA32(af[mf], bfv[nf], acc[mf][nf]);
    __syncthreads();
  }

  // C/D layout: col = lane&15, row = (lane>>4)*4 + reg
  if constexpr (MODE == 0) {
    bf16* Qb = (bf16*)(wsp + QOFF);
    bf16* Kb = (bf16*)(wsp + KOFF);
    bf16* Vw = (bf16*)(wsp + VOFF);
#pragma unroll
    for (int nf = 0; nf < 4; ++nf) {
      const int colb = bn * 128 + wc * 64 + nf * 16 + l15; // e in [0,3072)
      const int s = colb >> 10;          // 0:q 1:k 2:v
      const int h = (colb >> 6) & 15;
      const int d = colb & 63;
#pragma unroll
      for (int mf = 0; mf < 4; ++mf) {
        const int rowb = bm * 128 + wr * 64 + mf * 16 + g * 4;  // rr base
        const int bb = rowb >> 11;
        const int lib = rowb & 2047;
        if (s == 2) {
          // V: group = (lc>>3)^(d&7); pos = (lc&7)^(((d>>3)&1)<<2).
          const int lcb = lib & 63;
          const int swb = (((lcb >> 3) ^ (d & 7)) << 3) |
                          ((lcb & 7) ^ (((d >> 3) & 1) << 2));
          bf16x4 pv;
#pragma unroll
          for (int rr = 0; rr < 4; ++rr) pv[rr] = (bf16)acc[mf][nf][rr];
          *(bf16x4*)&Vw[(long)(bb * 16 + h) * 131072 + (lib >> 6) * 4096 +
                        d * 64 + swb] = pv;
        } else if (s == 0) {
#pragma unroll
          for (int rr = 0; rr < 4; ++rr)
            Qb[(long)((bb * 16 + h) * 2048 + lib + rr) * 64 + d] =
              (bf16)(acc[mf][nf][rr] * QSCALE);
        } else {
          // K: group = ((d>>3)^(li&7)) ^ (((li>>3)&1)<<2); pos = d&7.
#pragma unroll
          for (int rr = 0; rr < 4; ++rr) {
            const int li = lib + rr;
            const int sw = (((((d >> 3) ^ (li & 7)) ^ (((li >> 3) & 1) << 2)) << 3)
                            | (d & 7));
            Kb[(long)((bb * 16 + h) * 2048 + li) * 64 + sw] = (bf16)acc[mf][nf][rr];
          }
        }
      }
    }
  } else {
#pragma unroll
    for (int nf = 0; nf < 4; ++nf) {
      const int colg = bn * 128 + wc * 64 + nf * 16 + l15;
      const float bv = bias[colg];
#pragma unroll
      for (int mf = 0; mf < 4; ++mf) {
#pragma unroll
        for (int rr = 0; rr < 4; ++rr) {
          const int rowg = bm * 128 + wr * 64 + mf * 16 + g * 4 + rr;
          outp[(long)rowg * 1024 + colg] = acc[mf][nf][rr] + bv;
        }
      }
    }
  }
}

// Flash attention, swapped-operand, pipelined: S(t+1) MFMAs issued before
// softmax(t). K staged 2-ahead, V 1-ahead. Online defer-max softmax (guard).
// T5 setprio around MFMA clusters; conflict-free K reads; pure-VALU max reduce.
__global__ __launch_bounds__(256, 4)
void attn_fwd(const bf16* __restrict__ Q, const bf16* __restrict__ Kw,
              const bf16* __restrict__ Vw, bf16* __restrict__ Of)
{
  const int bid  = blockIdx.x;
  const int slot = bid >> 3;
  const int bh   = (bid & 7) * 4 + (slot >> 5);
  const int qt   = slot & 31;
  const int lane = threadIdx.x & 63;
  const int wave = threadIdx.x >> 6;
  const int l15  = lane & 15, g = lane >> 4;

  const bf16* Qh = Q  + (long)bh * 131072;
  const bf16* Ks = Kw + (long)bh * 131072;
  const bf16* Vs = Vw + (long)bh * 131072;

  __shared__ __align__(16) bf16 Klds[2][4096];
  __shared__ __align__(16) bf16 Vlds[2][4096];

  const int q0 = qt * 64 + wave * 16;

  bf16x8 qf[2];
#pragma unroll
  for (int ds = 0; ds < 2; ++ds)
    qf[ds] = *(const bf16x8*)(Qh + (q0 + l15) * 64 + ds * 32 + g * 8);

  int ke[2], ve[4];
#pragma unroll
  for (int ds = 0; ds < 2; ++ds)
    ke[ds] = l15 * 64 + ((((ds * 4 + g) ^ (l15 & 7)) ^ (((l15 >> 3) & 1) << 2)) << 3);
  const int hsw = ((g & 1) ^ ((l15 >> 3) & 1)) << 2;
#pragma unroll
  for (int kg = 0; kg < 4; ++kg)
    ve[kg] = l15 * 64 + (((2 * kg + (g >> 1)) ^ (l15 & 7)) << 3) + hsw;

  auto stageK = [&](int t, int buf) {
    const bf16* sk = Ks + t * 4096 + wave * 1024 + lane * 8;
    gl16(sk,       &Klds[buf][wave * 1024]);
    gl16(sk + 512, &Klds[buf][wave * 1024 + 512]);
  };
  auto stageV = [&](int t, int buf) {
    const bf16* sv = Vs + t * 4096 + wave * 1024 + lane * 8;
    gl16(sv,       &Vlds[buf][wave * 1024]);
    gl16(sv + 512, &Vlds[buf][wave * 1024 + 512]);
  };

  f32x4 o[4] = {};
  float m = -1e30f, ps = 0.f;
  f32x4 sfA[4], sfB[4];

#define COMPUTE_S(BUF, SF) do {                                               \
  __builtin_amdgcn_s_setprio(1);                                              \
  _Pragma("unroll")                                                           \
  for (int kg = 0; kg < 4; ++kg) {                                            \
    SF[kg] = f32x4{0.f, 0.f, 0.f, 0.f};                                       \
    _Pragma("unroll")                                                         \
    for (int ds = 0; ds < 2; ++ds) {                                          \
      const bf16x8 kf = *(const bf16x8*)&Klds[BUF][kg * 1024 + ke[ds]];       \
      SF[kg] = MFMA32(kf, qf[ds], SF[kg]);                                    \
    }                                                                         \
  }                                                                           \
  __builtin_amdgcn_s_setprio(0);                                              \
} while (0)

#define ATTN_BODY(T, SFC, SFN) do {                                           \
  if ((T) <= 29) stageK((T) + 2, (T) & 1);                                    \
  if ((T) <= 30) stageV((T) + 1, ((T) + 1) & 1);                              \
  if ((T) <= 30) COMPUTE_S(((T) + 1) & 1, SFN);                               \
  const float t0 = max3f(SFC[0][0], SFC[0][1], SFC[0][2]);                    \
  const float t1 = max3f(SFC[0][3], SFC[1][0], SFC[1][1]);                    \
  const float t2 = max3f(SFC[1][2], SFC[1][3], SFC[2][0]);                    \
  const float t3 = max3f(SFC[2][1], SFC[2][2], SFC[2][3]);                    \
  const float t4 = max3f(SFC[3][0], SFC[3][1], SFC[3][2]);                    \
  float tm = fmaxf(max3f(t0, t1, t2), max3f(t3, t4, SFC[3][3]));              \
  tm = xmax16(tm);                                                            \
  tm = xmax32(tm);                                                            \
  if (!__all(tm <= m + 8.f)) {                                                \
    const float nm = fmaxf(m, tm);                                            \
    const float al = exp2fast(m - nm);                                        \
    m = nm;                                                                   \
    ps *= al;                                                                 \
    _Pragma("unroll")                                                         \
    for (int dg = 0; dg < 4; ++dg)                                            \
      _Pragma("unroll")                                                       \
      for (int rr = 0; rr < 4; ++rr) o[dg][rr] *= al;                         \
  }                                                                           \
  bf16x4 pa[4];                                                               \
  float rs0 = 0.f, rs1 = 0.f, rs2 = 0.f, rs3 = 0.f;                           \
  _Pragma("unroll")                                                           \
  for (int kg = 0; kg < 4; ++kg) {                                            \
    const float p0 = exp2fast(SFC[kg][0] - m);                                \
    const float p1 = exp2fast(SFC[kg][1] - m);                                \
    const float p2 = exp2fast(SFC[kg][2] - m);                                \
    const float p3 = exp2fast(SFC[kg][3] - m);                                \
    rs0 += p0; rs1 += p1; rs2 += p2; rs3 += p3;                               \
    pa[kg][0] = (bf16)p0; pa[kg][1] = (bf16)p1;                               \
    pa[kg][2] = (bf16)p2; pa[kg][3] = (bf16)p3;                               \
  }                                                                           \
  ps += (rs0 + rs1) + (rs2 + rs3);                                            \
  __builtin_amdgcn_s_setprio(1);                                              \
  _Pragma("unroll")                                                           \
  for (int kg = 0; kg < 4; ++kg)                                              \
    _Pragma("unroll")                                                         \
    for (int dg = 0; dg < 4; ++dg) {                                          \
      const bf16x4 vb = *(const bf16x4*)&Vlds[(T) & 1][dg * 1024 + ve[kg]];   \
      o[dg] = mfma16(vb, pa[kg], o[dg]);                                      \
    }                                                                         \
  __builtin_amdgcn_s_setprio(0);                                              \
  __syncthreads();                                                            \
} while (0)

  // prologue: K0,V0 staged+drained; S(0) computed; K1 staged+drained
  stageK(0, 0);
  stageV(0, 0);
  __syncthreads();
  stageK(1, 1);
  COMPUTE_S(0, sfA);
  __syncthreads();

#pragma unroll 1
  for (int tp = 0; tp < 32; tp += 2) {
    ATTN_BODY(tp, sfA, sfB);
    ATTN_BODY(tp + 1, sfB, sfA);
  }

#undef ATTN_BODY
#undef COMPUTE_S

  ps += __shfl_xor(ps, 16);
  ps += __shfl_xor(ps, 32);
  const float inv = 1.f / ps;

  const int b = bh >> 4, h = bh & 15;
#pragma unroll
  for (int dg = 0; dg < 4; ++dg) {
    bf16x4 ov;
#pragma unroll
    for (int rr = 0; rr < 4; ++rr) ov[rr] = (bf16)(o[dg][rr] * inv);
    *(bf16x4*)(Of + (long)(b * 2048 + q0 + l15) * 1024 + h * 64 + dg * 16 + g * 4) = ov;
  }
}

extern "C" void kernel_launch(void* const* d_in, const int* in_sizes, int n_in,
                              void* d_out, int out_size, void* d_ws, size_t ws_size,
                              hipStream_t stream)
{
  (void)in_sizes; (void)n_in; (void)out_size; (void)ws_size;
  const float* x     = (const float*)d_in[0];
  const float* w_qkv = (const float*)d_in[1];
  const float* w_out = (const float*)d_in[2];
  const float* b_out = (const float*)d_in[3];
  float* out = (float*)d_out;
  char*  ws  = (char*)d_ws;

  bf16* Qb  = (bf16*)(ws + QOFF);
  bf16* Kb  = (bf16*)(ws + KOFF);
  bf16* Vw  = (bf16*)(ws + VOFF);
  bf16* xb  = (bf16*)(ws + FOFF);
  bf16* Ofb = (bf16*)(ws + FOFF);   // reuses xb region after gemm0 completes
  bf16* wqb = (bf16*)(ws + WQOFF);
  bf16* wob = (bf16*)(ws + WOOFF);

  cvt_all<<<dim3(4096), 256, 0, stream>>>(x, w_qkv, w_out, xb, wqb, wob);
  gemm_bt<0><<<dim3(24, 32), 256, 0, stream>>>(xb, wqb, nullptr, nullptr, ws);
  attn_fwd<<<dim3(1024), 256, 0, stream>>>(Qb, Kb, Vw, Ofb);
  gemm_bt<1><<<dim3(8, 32), 256, 0, stream>>>(Ofb, wob, out, b_out, ws);
}